// Round 5
// baseline (469.733 us; speedup 1.0000x reference)
//
#include <hip/hip_runtime.h>
#include <stdint.h>

#define NB 32
#define SEQ 577
#define SPAD 640
#define NH 16
#define HD 64
#define DM 1024
#define MTOT (NB * SEQ) /* 18464 */

typedef __bf16 bf16x8 __attribute__((ext_vector_type(8)));
typedef float f32x4 __attribute__((ext_vector_type(4)));
typedef unsigned short u16x8 __attribute__((ext_vector_type(8)));
typedef unsigned short u16x4 __attribute__((ext_vector_type(4)));

__device__ __forceinline__ unsigned short f2bf(float f) {
  unsigned int u = __builtin_bit_cast(unsigned int, f);
  return (unsigned short)((u + 0x7FFFu + ((u >> 16) & 1u)) >> 16);
}

__device__ __forceinline__ f32x4 mfma16(bf16x8 a, bf16x8 b, f32x4 c) {
  return __builtin_amdgcn_mfma_f32_16x16x32_bf16(a, b, c, 0, 0, 0);
}

__device__ __forceinline__ void gload16(const unsigned short* g, unsigned short* l) {
  __builtin_amdgcn_global_load_lds(
      (const __attribute__((address_space(1))) unsigned int*)g,
      (__attribute__((address_space(3))) unsigned int*)l, 16, 0, 0);
}

#if __has_builtin(__builtin_amdgcn_exp2f)
#define EXP2(x) __builtin_amdgcn_exp2f(x)
#else
#define EXP2(x) exp2f(x)
#endif

// ---------------- fp32 -> bf16 conversion of x and the 3 weight matrices ----
__global__ void cvt_kernel(const float* __restrict__ x,
                           const float* __restrict__ wq,
                           const float* __restrict__ wk,
                           const float* __restrict__ wv,
                           unsigned short* __restrict__ xb,
                           unsigned short* __restrict__ wb) {
  const long long NX = (long long)MTOT * DM;
  long long i = ((long long)blockIdx.x * blockDim.x + threadIdx.x) * 4;
  const float* src;
  unsigned short* dst;
  if (i < NX) {
    src = x + i;
    dst = xb + i;
  } else {
    long long j = i - NX;                 // 0 .. 3*2^20-1, DM*DM = 2^20
    int wsel = (int)(j >> 20);
    long long off = j & 0xFFFFF;
    src = (wsel == 0 ? wq : wsel == 1 ? wk : wv) + off;
    dst = wb + j;
  }
  f32x4 v = *(const f32x4*)src;
  u16x4 o;
  o.x = f2bf(v.x); o.y = f2bf(v.y); o.z = f2bf(v.z); o.w = f2bf(v.w);
  *(u16x4*)dst = o;
}

// ---------------- fused QKV projection: C = x @ W^T + b ---------------------
// v2: 1-D grid, XCD-aware swizzle (id&7 = XCD owns 3 fixed (n,z) tiles ->
// W L2-resident; 3 same-m blocks temporally adjacent -> A fetched ~once/XCD).
// z=2 computes C^T via operand swap so V^T stores are coalesced along s.
__global__ __launch_bounds__(256, 2) void qkv_gemm(
    const unsigned short* __restrict__ xb, const unsigned short* __restrict__ wb,
    const float* __restrict__ bq, const float* __restrict__ bk,
    const float* __restrict__ bv, unsigned short* __restrict__ qo,
    unsigned short* __restrict__ ko, unsigned short* __restrict__ vo) {
  const int id = blockIdx.x;
  const int xcd = id & 7;
  const int slot = id >> 3;      // 0..455
  const int m_tile = slot / 3;   // 0..151 (145..151 dummy)
  if (m_tile >= 145) return;
  const int nz = xcd * 3 + (slot - m_tile * 3);  // 0..23
  const int z = nz >> 3;
  const int n0 = (nz & 7) * 128;
  const int m0 = m_tile * 128;

  __shared__ __align__(16) unsigned short As[128 * 32];
  __shared__ __align__(16) unsigned short Bs[128 * 32];
  const int t = threadIdx.x;
  const unsigned short* W = wb + (size_t)z * (DM * DM);
  const float* bias = (z == 0 ? bq : z == 1 ? bk : bv);

  const int lane = t & 63;
  const int g = lane >> 4, c = lane & 15;
  const int w = t >> 6;
  const int wm = w & 1, wn = w >> 1;

  const int srow = t >> 2;
  const int scol = (t & 3) * 8;
  int ar0 = m0 + srow;      if (ar0 > MTOT - 1) ar0 = MTOT - 1;
  int ar1 = m0 + 64 + srow; if (ar1 > MTOT - 1) ar1 = MTOT - 1;
  const unsigned short* gA0 = xb + (size_t)ar0 * DM + scol;
  const unsigned short* gA1 = xb + (size_t)ar1 * DM + scol;
  const unsigned short* gB0 = W + (size_t)(n0 + srow) * DM + scol;
  const unsigned short* gB1 = W + (size_t)(n0 + 64 + srow) * DM + scol;
  unsigned short* lA0 = As + t * 8;
  unsigned short* lA1 = As + 2048 + t * 8;
  unsigned short* lB0 = Bs + t * 8;
  unsigned short* lB1 = Bs + 2048 + t * 8;

  f32x4 acc[4][4];
#pragma unroll
  for (int mi = 0; mi < 4; mi++)
#pragma unroll
    for (int ni = 0; ni < 4; ni++) acc[mi][ni] = (f32x4)0.0f;

  for (int k0 = 0; k0 < DM; k0 += 32) {
    __syncthreads();
    gload16(gA0 + k0, lA0);
    gload16(gA1 + k0, lA1);
    gload16(gB0 + k0, lB0);
    gload16(gB1 + k0, lB1);
    __syncthreads();
    bf16x8 af[4], bfr[4];
#pragma unroll
    for (int mi = 0; mi < 4; mi++)
      af[mi] = __builtin_bit_cast(
          bf16x8, *(const u16x8*)(As + (wm * 64 + mi * 16 + c) * 32 + g * 8));
#pragma unroll
    for (int ni = 0; ni < 4; ni++)
      bfr[ni] = __builtin_bit_cast(
          bf16x8, *(const u16x8*)(Bs + (wn * 64 + ni * 16 + c) * 32 + g * 8));
    if (z == 2) {  // C^T: rows = n, cols = m
#pragma unroll
      for (int mi = 0; mi < 4; mi++)
#pragma unroll
        for (int ni = 0; ni < 4; ni++)
          acc[mi][ni] = mfma16(bfr[ni], af[mi], acc[mi][ni]);
    } else {
#pragma unroll
      for (int mi = 0; mi < 4; mi++)
#pragma unroll
        for (int ni = 0; ni < 4; ni++)
          acc[mi][ni] = mfma16(af[mi], bfr[ni], acc[mi][ni]);
    }
  }

  if (z == 2) {
    // acc[mi][ni] element (r, c): n = n0+wn*64+ni*16+g*4+r, m = m0+wm*64+mi*16+c
#pragma unroll
    for (int ni = 0; ni < 4; ni++) {
#pragma unroll
      for (int r = 0; r < 4; r++) {
        int n = n0 + wn * 64 + ni * 16 + g * 4 + r;
        int hh = n >> 6, dd = n & 63;
        float bn = bias[n];
#pragma unroll
        for (int mi = 0; mi < 4; mi++) {
          int m = m0 + wm * 64 + mi * 16 + c;
          if (m >= MTOT) continue;
          int bi = m / SEQ;
          int s = m - bi * SEQ;
          vo[(((size_t)bi * NH + hh) * HD + dd) * SPAD + s] =
              f2bf(acc[mi][ni][r] + bn);  // lanes c -> consecutive s
        }
      }
    }
  } else {
    float bias4[4];
#pragma unroll
    for (int ni = 0; ni < 4; ni++) bias4[ni] = bias[n0 + wn * 64 + ni * 16 + c];
#pragma unroll
    for (int mi = 0; mi < 4; mi++) {
      int mb = m0 + wm * 64 + mi * 16 + g * 4;
#pragma unroll
      for (int r = 0; r < 4; r++) {
        int m = mb + r;
        if (m >= MTOT) continue;
        int bi = m / SEQ;
        int s = m - bi * SEQ;
#pragma unroll
        for (int ni = 0; ni < 4; ni++) {
          int n = n0 + wn * 64 + ni * 16 + c;
          int hh = n >> 6, dd = n & 63;
          unsigned short v = f2bf(acc[mi][ni][r] + bias4[ni]);
          if (z == 0)
            qo[(((size_t)bi * NH + hh) * SPAD + s) * HD + dd] = v;
          else
            ko[(((size_t)bi * NH + hh) * SPAD + s) * HD + dd] = v;
        }
      }
    }
  }
}

// ---------------- flash attention v2 (unchanged from R4 PASS) ---------------
__global__ __launch_bounds__(256, 4) void attn_kernel(
    const unsigned short* __restrict__ Qb, const unsigned short* __restrict__ Kb,
    const unsigned short* __restrict__ Vt, float* __restrict__ out) {
  __shared__ __align__(16) unsigned short Ks[64 * 64];   // [kv][d], swizzled
  __shared__ __align__(16) unsigned short Vs[80 * 64];   // [d][kv]; rows 64..79 const
  __shared__ __align__(16) unsigned short Pl[4][16 * 72];
  const int t = threadIdx.x, lane = t & 63, w = t >> 6;
  const int g = lane >> 4, c = lane & 15;
  const int qt = blockIdx.x, h = blockIdx.y, b = blockIdx.z;
  const int q0 = qt * 64 + w * 16;
  const size_t bh = (size_t)b * NH + h;
  const unsigned short* Qp = Qb + bh * SPAD * HD;
  const unsigned short* Kp = Kb + bh * SPAD * HD;
  const unsigned short* Vp = Vt + bh * HD * SPAD;

  {
    int rr = t >> 4, col = (t & 15) * 4;
    unsigned short val = (rr == 0) ? (unsigned short)0x3F80 : (unsigned short)0;
    u16x4 v4 = {val, val, val, val};
    *(u16x4*)(Vs + (64 + rr) * 64 + col) = v4;
  }

  bf16x8 qf0 = __builtin_bit_cast(
      bf16x8, *(const u16x8*)(Qp + (size_t)(q0 + c) * HD + g * 8));
  bf16x8 qf1 = __builtin_bit_cast(
      bf16x8, *(const u16x8*)(Qp + (size_t)(q0 + c) * HD + 32 + g * 8));

  const int C0 = t, C1 = t + 256;
  const int r0 = C0 >> 3, cg0 = (C0 & 7) ^ (r0 & 7);
  const int r1 = C1 >> 3, cg1 = (C1 & 7) ^ (r1 & 7);
  const unsigned short* gK0 = Kp + (size_t)(r0 * 8 + cg0) * 8;
  const unsigned short* gK1 = Kp + (size_t)(r1 * 8 + cg1) * 8;
  const unsigned short* gV0 = Vp + (size_t)r0 * SPAD + cg0 * 8;
  const unsigned short* gV1 = Vp + (size_t)r1 * SPAD + cg1 * 8;
  unsigned short* lK0 = Ks + C0 * 8;
  unsigned short* lK1 = Ks + C1 * 8;
  unsigned short* lV0 = Vs + C0 * 8;
  unsigned short* lV1 = Vs + C1 * 8;

  f32x4 oacc[5];
#pragma unroll
  for (int nt = 0; nt < 5; nt++) oacc[nt] = (f32x4)0.0f;
  unsigned short* pl = &Pl[w][0];
  const float SC = 0.125f * 1.44269504f;

  for (int kt = 0; kt < 10; kt++) {
    const int kv0 = kt * 64;
    __syncthreads();
    gload16(gK0 + kv0 * 64, lK0);
    gload16(gK1 + kv0 * 64, lK1);
    gload16(gV0 + kv0, lV0);
    gload16(gV1 + kv0, lV1);
    __syncthreads();

    f32x4 sc[4];
#pragma unroll
    for (int nt = 0; nt < 4; nt++) {
      const int row = nt * 16 + c;
      const unsigned short* kb = Ks + row * 64;
      bf16x8 k0 = __builtin_bit_cast(
          bf16x8, *(const u16x8*)(kb + ((g ^ (row & 7)) * 8)));
      bf16x8 k1 = __builtin_bit_cast(
          bf16x8, *(const u16x8*)(kb + (((4 + g) ^ (row & 7)) * 8)));
      sc[nt] = mfma16(qf0, k0, (f32x4)0.0f);
      sc[nt] = mfma16(qf1, k1, sc[nt]);
    }

    if (kt == 9) {
#pragma unroll
      for (int nt = 0; nt < 4; nt++) {
        const bool valid = (kv0 + nt * 16 + c) < SEQ;
#pragma unroll
        for (int r = 0; r < 4; r++)
          sc[nt][r] = valid ? EXP2(sc[nt][r] * SC) : 0.0f;
      }
    } else {
#pragma unroll
      for (int nt = 0; nt < 4; nt++)
#pragma unroll
        for (int r = 0; r < 4; r++) sc[nt][r] = EXP2(sc[nt][r] * SC);
    }

#pragma unroll
    for (int nt = 0; nt < 4; nt++)
#pragma unroll
      for (int r = 0; r < 4; r++)
        pl[(g * 4 + r) * 72 + nt * 16 + c] = f2bf(sc[nt][r]);
    bf16x8 pa0 = __builtin_bit_cast(bf16x8, *(const u16x8*)(pl + c * 72 + g * 8));
    bf16x8 pa1 =
        __builtin_bit_cast(bf16x8, *(const u16x8*)(pl + c * 72 + 32 + g * 8));

#pragma unroll
    for (int nt = 0; nt < 5; nt++) {
      const int row = nt * 16 + c;
      const unsigned short* vb = Vs + row * 64;
      bf16x8 v0 = __builtin_bit_cast(
          bf16x8, *(const u16x8*)(vb + ((g ^ (row & 7)) * 8)));
      bf16x8 v1 = __builtin_bit_cast(
          bf16x8, *(const u16x8*)(vb + (((4 + g) ^ (row & 7)) * 8)));
      oacc[nt] = mfma16(pa0, v0, oacc[nt]);
      oacc[nt] = mfma16(pa1, v1, oacc[nt]);
    }
  }

#pragma unroll
  for (int r = 0; r < 4; r++) {
    int s = q0 + g * 4 + r;
    if (s >= SEQ) continue;
    float l = __shfl(oacc[4][r], lane & 48, 64);
    float inv = 1.0f / l;
#pragma unroll
    for (int nt = 0; nt < 4; nt++)
      out[((size_t)b * SEQ + s) * DM + h * HD + nt * 16 + c] =
          oacc[nt][r] * inv;
  }
}

extern "C" void kernel_launch(void* const* d_in, const int* in_sizes, int n_in,
                              void* d_out, int out_size, void* d_ws,
                              size_t ws_size, hipStream_t stream) {
  const float* x = (const float*)d_in[0];
  const float* Wq = (const float*)d_in[1];
  const float* bq = (const float*)d_in[2];
  const float* Wk = (const float*)d_in[3];
  const float* bk = (const float*)d_in[4];
  const float* Wv = (const float*)d_in[5];
  const float* bv = (const float*)d_in[6];
  float* out = (float*)d_out;

  const size_t nXB = (size_t)MTOT * DM;
  const size_t nWB = (size_t)3 * DM * DM;
  const size_t nQK = (size_t)NB * NH * SPAD * HD;
  const size_t needed = (nXB + nWB + 3 * nQK) * 2;
  if (ws_size < needed) return;

  unsigned short* xb = (unsigned short*)d_ws;
  unsigned short* wb = xb + nXB;
  unsigned short* Qb = wb + nWB;
  unsigned short* Kb = Qb + nQK;
  unsigned short* Vt = Kb + nQK;

  cvt_kernel<<<21536, 256, 0, stream>>>(x, Wq, Wk, Wv, xb, wb);
  qkv_gemm<<<3648, 256, 0, stream>>>(xb, wb, bq, bk, bv, Qb, Kb, Vt);
  attn_kernel<<<dim3(10, NH, NB), 256, 0, stream>>>(Qb, Kb, Vt, out);
}

// Round 6
// 428.258 us; speedup vs baseline: 1.0968x; 1.0968x over previous
//
#include <hip/hip_runtime.h>
#include <stdint.h>

#define NB 32
#define SEQ 577
#define SPAD 640
#define NH 16
#define HD 64
#define DM 1024
#define MTOT (NB * SEQ) /* 18464 */

typedef __bf16 bf16x8 __attribute__((ext_vector_type(8)));
typedef float f32x4 __attribute__((ext_vector_type(4)));
typedef unsigned short u16x8 __attribute__((ext_vector_type(8)));
typedef unsigned short u16x4 __attribute__((ext_vector_type(4)));

__device__ __forceinline__ unsigned short f2bf(float f) {
  unsigned int u = __builtin_bit_cast(unsigned int, f);
  return (unsigned short)((u + 0x7FFFu + ((u >> 16) & 1u)) >> 16);
}

__device__ __forceinline__ f32x4 mfma16(bf16x8 a, bf16x8 b, f32x4 c) {
  return __builtin_amdgcn_mfma_f32_16x16x32_bf16(a, b, c, 0, 0, 0);
}

__device__ __forceinline__ void gload16(const unsigned short* g, unsigned short* l) {
  __builtin_amdgcn_global_load_lds(
      (const __attribute__((address_space(1))) unsigned int*)g,
      (__attribute__((address_space(3))) unsigned int*)l, 16, 0, 0);
}

#if __has_builtin(__builtin_amdgcn_exp2f)
#define EXP2(x) __builtin_amdgcn_exp2f(x)
#else
#define EXP2(x) exp2f(x)
#endif

// ---------------- fp32 -> bf16 conversion of x and the 3 weight matrices ----
__global__ void cvt_kernel(const float* __restrict__ x,
                           const float* __restrict__ wq,
                           const float* __restrict__ wk,
                           const float* __restrict__ wv,
                           unsigned short* __restrict__ xb,
                           unsigned short* __restrict__ wb) {
  const long long NX = (long long)MTOT * DM;
  long long i = ((long long)blockIdx.x * blockDim.x + threadIdx.x) * 4;
  const float* src;
  unsigned short* dst;
  if (i < NX) {
    src = x + i;
    dst = xb + i;
  } else {
    long long j = i - NX;                 // 0 .. 3*2^20-1, DM*DM = 2^20
    int wsel = (int)(j >> 20);
    long long off = j & 0xFFFFF;
    src = (wsel == 0 ? wq : wsel == 1 ? wk : wv) + off;
    dst = wb + j;
  }
  f32x4 v = *(const f32x4*)src;
  u16x4 o;
  o.x = f2bf(v.x); o.y = f2bf(v.y); o.z = f2bf(v.z); o.w = f2bf(v.w);
  *(u16x4*)dst = o;
}

// ---------------- Q/K projection: C = x @ W^T + b ---------------------------
// Single code path (normal orientation). XCD-aware: id&7 = xcd owns 2 (n,z)
// W-blocks (512 KB, L2-resident); m iterated with same-m blocks adjacent.
__global__ __launch_bounds__(256, 2) void qk_gemm(
    const unsigned short* __restrict__ xb, const unsigned short* __restrict__ wb,
    const float* __restrict__ bq, const float* __restrict__ bk,
    unsigned short* __restrict__ qo, unsigned short* __restrict__ ko) {
  const int id = blockIdx.x;
  const int xcd = id & 7;
  const int slot = id >> 3;        // 0..289
  const int m_tile = slot >> 1;    // 0..144
  const int nz = xcd * 2 + (slot & 1);  // 0..15
  const int z = nz >> 3;
  const int n0 = (nz & 7) * 128;
  const int m0 = m_tile * 128;

  __shared__ __align__(16) unsigned short As[128 * 32];
  __shared__ __align__(16) unsigned short Bs[128 * 32];
  const int t = threadIdx.x;
  const unsigned short* W = wb + (size_t)z * (DM * DM);
  const float* bias = (z == 0 ? bq : bk);
  unsigned short* outp = (z == 0 ? qo : ko);

  const int lane = t & 63;
  const int g = lane >> 4, c = lane & 15;
  const int w = t >> 6;
  const int wm = w & 1, wn = w >> 1;

  const int srow = t >> 2;
  const int scol = (t & 3) * 8;
  int ar0 = m0 + srow;      if (ar0 > MTOT - 1) ar0 = MTOT - 1;
  int ar1 = m0 + 64 + srow; if (ar1 > MTOT - 1) ar1 = MTOT - 1;
  const unsigned short* gA0 = xb + (size_t)ar0 * DM + scol;
  const unsigned short* gA1 = xb + (size_t)ar1 * DM + scol;
  const unsigned short* gB0 = W + (size_t)(n0 + srow) * DM + scol;
  const unsigned short* gB1 = W + (size_t)(n0 + 64 + srow) * DM + scol;
  unsigned short* lA0 = As + t * 8;
  unsigned short* lA1 = As + 2048 + t * 8;
  unsigned short* lB0 = Bs + t * 8;
  unsigned short* lB1 = Bs + 2048 + t * 8;

  f32x4 acc[4][4];
#pragma unroll
  for (int mi = 0; mi < 4; mi++)
#pragma unroll
    for (int ni = 0; ni < 4; ni++) acc[mi][ni] = (f32x4)0.0f;

  for (int k0 = 0; k0 < DM; k0 += 32) {
    __syncthreads();
    gload16(gA0 + k0, lA0);
    gload16(gA1 + k0, lA1);
    gload16(gB0 + k0, lB0);
    gload16(gB1 + k0, lB1);
    __syncthreads();
    bf16x8 af[4], bfr[4];
#pragma unroll
    for (int mi = 0; mi < 4; mi++)
      af[mi] = __builtin_bit_cast(
          bf16x8, *(const u16x8*)(As + (wm * 64 + mi * 16 + c) * 32 + g * 8));
#pragma unroll
    for (int ni = 0; ni < 4; ni++)
      bfr[ni] = __builtin_bit_cast(
          bf16x8, *(const u16x8*)(Bs + (wn * 64 + ni * 16 + c) * 32 + g * 8));
#pragma unroll
    for (int mi = 0; mi < 4; mi++)
#pragma unroll
      for (int ni = 0; ni < 4; ni++)
        acc[mi][ni] = mfma16(af[mi], bfr[ni], acc[mi][ni]);
  }

  float bias4[4];
#pragma unroll
  for (int ni = 0; ni < 4; ni++) bias4[ni] = bias[n0 + wn * 64 + ni * 16 + c];

#pragma unroll
  for (int mi = 0; mi < 4; mi++) {
    int mb = m0 + wm * 64 + mi * 16 + g * 4;
#pragma unroll
    for (int r = 0; r < 4; r++) {
      int m = mb + r;
      if (m >= MTOT) continue;
      int bi = m / SEQ;
      int s = m - bi * SEQ;
#pragma unroll
      for (int ni = 0; ni < 4; ni++) {
        int n = n0 + wn * 64 + ni * 16 + c;
        int hh = n >> 6, dd = n & 63;
        outp[(((size_t)bi * NH + hh) * SPAD + s) * HD + dd] =
            f2bf(acc[mi][ni][r] + bias4[ni]);
      }
    }
  }
}

// ---------------- V projection, transposed out: C^T via operand swap --------
// Single code path. xcd owns 1 W-block (256 KB). Stores coalesced along s.
__global__ __launch_bounds__(256, 2) void vt_gemm(
    const unsigned short* __restrict__ xb, const unsigned short* __restrict__ wb,
    const float* __restrict__ bv, unsigned short* __restrict__ vo) {
  const int id = blockIdx.x;
  const int xcd = id & 7;
  const int m_tile = id >> 3;   // 0..144
  const int n0 = xcd * 128;
  const int m0 = m_tile * 128;

  __shared__ __align__(16) unsigned short As[128 * 32];
  __shared__ __align__(16) unsigned short Bs[128 * 32];
  const int t = threadIdx.x;
  const unsigned short* W = wb + (size_t)2 * (DM * DM);

  const int lane = t & 63;
  const int g = lane >> 4, c = lane & 15;
  const int w = t >> 6;
  const int wm = w & 1, wn = w >> 1;

  const int srow = t >> 2;
  const int scol = (t & 3) * 8;
  int ar0 = m0 + srow;      if (ar0 > MTOT - 1) ar0 = MTOT - 1;
  int ar1 = m0 + 64 + srow; if (ar1 > MTOT - 1) ar1 = MTOT - 1;
  const unsigned short* gA0 = xb + (size_t)ar0 * DM + scol;
  const unsigned short* gA1 = xb + (size_t)ar1 * DM + scol;
  const unsigned short* gB0 = W + (size_t)(n0 + srow) * DM + scol;
  const unsigned short* gB1 = W + (size_t)(n0 + 64 + srow) * DM + scol;
  unsigned short* lA0 = As + t * 8;
  unsigned short* lA1 = As + 2048 + t * 8;
  unsigned short* lB0 = Bs + t * 8;
  unsigned short* lB1 = Bs + 2048 + t * 8;

  f32x4 acc[4][4];  // [mi][ni], C^T orientation: rows=n, cols=m
#pragma unroll
  for (int mi = 0; mi < 4; mi++)
#pragma unroll
    for (int ni = 0; ni < 4; ni++) acc[mi][ni] = (f32x4)0.0f;

  for (int k0 = 0; k0 < DM; k0 += 32) {
    __syncthreads();
    gload16(gA0 + k0, lA0);
    gload16(gA1 + k0, lA1);
    gload16(gB0 + k0, lB0);
    gload16(gB1 + k0, lB1);
    __syncthreads();
    bf16x8 af[4], bfr[4];
#pragma unroll
    for (int mi = 0; mi < 4; mi++)
      af[mi] = __builtin_bit_cast(
          bf16x8, *(const u16x8*)(As + (wm * 64 + mi * 16 + c) * 32 + g * 8));
#pragma unroll
    for (int ni = 0; ni < 4; ni++)
      bfr[ni] = __builtin_bit_cast(
          bf16x8, *(const u16x8*)(Bs + (wn * 64 + ni * 16 + c) * 32 + g * 8));
#pragma unroll
    for (int mi = 0; mi < 4; mi++)
#pragma unroll
      for (int ni = 0; ni < 4; ni++)
        acc[mi][ni] = mfma16(bfr[ni], af[mi], acc[mi][ni]);  // swapped -> C^T
  }

  // acc[mi][ni] element (r, lane c): n = n0+wn*64+ni*16+g*4+r, m = m0+wm*64+mi*16+c
#pragma unroll
  for (int ni = 0; ni < 4; ni++) {
#pragma unroll
    for (int r = 0; r < 4; r++) {
      int n = n0 + wn * 64 + ni * 16 + g * 4 + r;
      int hh = n >> 6, dd = n & 63;
      float bn = bv[n];
#pragma unroll
      for (int mi = 0; mi < 4; mi++) {
        int m = m0 + wm * 64 + mi * 16 + c;
        if (m >= MTOT) continue;
        int bi = m / SEQ;
        int s = m - bi * SEQ;
        vo[(((size_t)bi * NH + hh) * HD + dd) * SPAD + s] =
            f2bf(acc[mi][ni][r] + bn);  // lanes c -> consecutive s
      }
    }
  }
}

// ---------------- flash attention v2 (unchanged from R4 PASS) ---------------
__global__ __launch_bounds__(256, 4) void attn_kernel(
    const unsigned short* __restrict__ Qb, const unsigned short* __restrict__ Kb,
    const unsigned short* __restrict__ Vt, float* __restrict__ out) {
  __shared__ __align__(16) unsigned short Ks[64 * 64];   // [kv][d], swizzled
  __shared__ __align__(16) unsigned short Vs[80 * 64];   // [d][kv]; rows 64..79 const
  __shared__ __align__(16) unsigned short Pl[4][16 * 72];
  const int t = threadIdx.x, lane = t & 63, w = t >> 6;
  const int g = lane >> 4, c = lane & 15;
  const int qt = blockIdx.x, h = blockIdx.y, b = blockIdx.z;
  const int q0 = qt * 64 + w * 16;
  const size_t bh = (size_t)b * NH + h;
  const unsigned short* Qp = Qb + bh * SPAD * HD;
  const unsigned short* Kp = Kb + bh * SPAD * HD;
  const unsigned short* Vp = Vt + bh * HD * SPAD;

  {
    int rr = t >> 4, col = (t & 15) * 4;
    unsigned short val = (rr == 0) ? (unsigned short)0x3F80 : (unsigned short)0;
    u16x4 v4 = {val, val, val, val};
    *(u16x4*)(Vs + (64 + rr) * 64 + col) = v4;
  }

  bf16x8 qf0 = __builtin_bit_cast(
      bf16x8, *(const u16x8*)(Qp + (size_t)(q0 + c) * HD + g * 8));
  bf16x8 qf1 = __builtin_bit_cast(
      bf16x8, *(const u16x8*)(Qp + (size_t)(q0 + c) * HD + 32 + g * 8));

  const int C0 = t, C1 = t + 256;
  const int r0 = C0 >> 3, cg0 = (C0 & 7) ^ (r0 & 7);
  const int r1 = C1 >> 3, cg1 = (C1 & 7) ^ (r1 & 7);
  const unsigned short* gK0 = Kp + (size_t)(r0 * 8 + cg0) * 8;
  const unsigned short* gK1 = Kp + (size_t)(r1 * 8 + cg1) * 8;
  const unsigned short* gV0 = Vp + (size_t)r0 * SPAD + cg0 * 8;
  const unsigned short* gV1 = Vp + (size_t)r1 * SPAD + cg1 * 8;
  unsigned short* lK0 = Ks + C0 * 8;
  unsigned short* lK1 = Ks + C1 * 8;
  unsigned short* lV0 = Vs + C0 * 8;
  unsigned short* lV1 = Vs + C1 * 8;

  f32x4 oacc[5];
#pragma unroll
  for (int nt = 0; nt < 5; nt++) oacc[nt] = (f32x4)0.0f;
  unsigned short* pl = &Pl[w][0];
  const float SC = 0.125f * 1.44269504f;

  for (int kt = 0; kt < 10; kt++) {
    const int kv0 = kt * 64;
    __syncthreads();
    gload16(gK0 + kv0 * 64, lK0);
    gload16(gK1 + kv0 * 64, lK1);
    gload16(gV0 + kv0, lV0);
    gload16(gV1 + kv0, lV1);
    __syncthreads();

    f32x4 sc[4];
#pragma unroll
    for (int nt = 0; nt < 4; nt++) {
      const int row = nt * 16 + c;
      const unsigned short* kb = Ks + row * 64;
      bf16x8 k0 = __builtin_bit_cast(
          bf16x8, *(const u16x8*)(kb + ((g ^ (row & 7)) * 8)));
      bf16x8 k1 = __builtin_bit_cast(
          bf16x8, *(const u16x8*)(kb + (((4 + g) ^ (row & 7)) * 8)));
      sc[nt] = mfma16(qf0, k0, (f32x4)0.0f);
      sc[nt] = mfma16(qf1, k1, sc[nt]);
    }

    if (kt == 9) {
#pragma unroll
      for (int nt = 0; nt < 4; nt++) {
        const bool valid = (kv0 + nt * 16 + c) < SEQ;
#pragma unroll
        for (int r = 0; r < 4; r++)
          sc[nt][r] = valid ? EXP2(sc[nt][r] * SC) : 0.0f;
      }
    } else {
#pragma unroll
      for (int nt = 0; nt < 4; nt++)
#pragma unroll
        for (int r = 0; r < 4; r++) sc[nt][r] = EXP2(sc[nt][r] * SC);
    }

#pragma unroll
    for (int nt = 0; nt < 4; nt++)
#pragma unroll
      for (int r = 0; r < 4; r++)
        pl[(g * 4 + r) * 72 + nt * 16 + c] = f2bf(sc[nt][r]);
    bf16x8 pa0 = __builtin_bit_cast(bf16x8, *(const u16x8*)(pl + c * 72 + g * 8));
    bf16x8 pa1 =
        __builtin_bit_cast(bf16x8, *(const u16x8*)(pl + c * 72 + 32 + g * 8));

#pragma unroll
    for (int nt = 0; nt < 5; nt++) {
      const int row = nt * 16 + c;
      const unsigned short* vb = Vs + row * 64;
      bf16x8 v0 = __builtin_bit_cast(
          bf16x8, *(const u16x8*)(vb + ((g ^ (row & 7)) * 8)));
      bf16x8 v1 = __builtin_bit_cast(
          bf16x8, *(const u16x8*)(vb + (((4 + g) ^ (row & 7)) * 8)));
      oacc[nt] = mfma16(pa0, v0, oacc[nt]);
      oacc[nt] = mfma16(pa1, v1, oacc[nt]);
    }
  }

#pragma unroll
  for (int r = 0; r < 4; r++) {
    int s = q0 + g * 4 + r;
    if (s >= SEQ) continue;
    float l = __shfl(oacc[4][r], lane & 48, 64);
    float inv = 1.0f / l;
#pragma unroll
    for (int nt = 0; nt < 4; nt++)
      out[((size_t)b * SEQ + s) * DM + h * HD + nt * 16 + c] =
          oacc[nt][r] * inv;
  }
}

extern "C" void kernel_launch(void* const* d_in, const int* in_sizes, int n_in,
                              void* d_out, int out_size, void* d_ws,
                              size_t ws_size, hipStream_t stream) {
  const float* x = (const float*)d_in[0];
  const float* Wq = (const float*)d_in[1];
  const float* bq = (const float*)d_in[2];
  const float* Wk = (const float*)d_in[3];
  const float* bk = (const float*)d_in[4];
  const float* Wv = (const float*)d_in[5];
  const float* bv = (const float*)d_in[6];
  float* out = (float*)d_out;

  const size_t nXB = (size_t)MTOT * DM;
  const size_t nWB = (size_t)3 * DM * DM;
  const size_t nQK = (size_t)NB * NH * SPAD * HD;
  const size_t needed = (nXB + nWB + 3 * nQK) * 2;
  if (ws_size < needed) return;

  unsigned short* xb = (unsigned short*)d_ws;
  unsigned short* wb = xb + nXB;
  unsigned short* Qb = wb + nWB;
  unsigned short* Kb = Qb + nQK;
  unsigned short* Vt = Kb + nQK;

  cvt_kernel<<<21536, 256, 0, stream>>>(x, Wq, Wk, Wv, xb, wb);
  qk_gemm<<<2320, 256, 0, stream>>>(xb, wb, bq, bk, Qb, Kb);
  vt_gemm<<<1160, 256, 0, stream>>>(xb, wb, bv, Vt);
  attn_kernel<<<dim3(10, NH, NB), 256, 0, stream>>>(Qb, Kb, Vt, out);
}